// Round 18
// baseline (129.615 us; speedup 1.0000x reference)
//
#include <hip/hip_runtime.h>
#include <stdint.h>

typedef unsigned short u16;
typedef __attribute__((ext_vector_type(8))) short bfrag8;       // 8 x bf16 (MFMA operand)
typedef __attribute__((ext_vector_type(4))) float f32x4;        // MFMA accumulator
typedef __attribute__((ext_vector_type(8))) unsigned short u16x8;
typedef __attribute__((ext_vector_type(4))) unsigned short u16x4;

__device__ __forceinline__ u16 f2bf(float f) {
  union { float f; uint32_t u; } v; v.f = f;
  return (u16)((v.u + 0x7FFFu + ((v.u >> 16) & 1u)) >> 16);   // RNE
}

// v_cvt_pk_bf16_f32: lo16=bf16(a), hi16=bf16(b) (no builtin on gfx950 -- T12 recipe)
__device__ __forceinline__ uint32_t cvtpk_bf16(float a, float b) {
  uint32_t r;
  asm("v_cvt_pk_bf16_f32 %0, %1, %2" : "=v"(r) : "v"(a), "v"(b));
  return r;
}

// async global->LDS, 16B per lane; LDS dest is wave-uniform base + lane*16
__device__ __forceinline__ void gload16(const void* g, void* l) {
  __builtin_amdgcn_global_load_lds(
      (const __attribute__((address_space(1))) void*)g,
      (__attribute__((address_space(3))) void*)l, 16, 0, 0);
}

// ---------------- fp32 -> bf16 convert, batched (7 tensors, 1 launch) ----------------
struct CvtJob { const float* src; u16* dst; int n4; };
struct CvtBatch { CvtJob j[7]; };

__global__ void cvt_batch(CvtBatch b) {
  CvtJob jb = b.j[blockIdx.y];
  int i = blockIdx.x * blockDim.x + threadIdx.x;
  if (i >= jb.n4) return;
  float4 v = reinterpret_cast<const float4*>(jb.src)[i];
  u16x4 o;
  o[0] = f2bf(v.x); o[1] = f2bf(v.y); o[2] = f2bf(v.z); o[3] = f2bf(v.w);
  reinterpret_cast<u16x4*>(jb.dst)[i] = o;
}

// ---------------- NT GEMM: C = A(M,K) @ W(N,K)^T + bias ----------------
// R10 K-loop (gload_lds staging, BK=64, XOR chunk swizzle, T3-minimal prefetch).
// R18 delta: z iterated INSIDE the kernel (grid 512, all resident) so each XCD's live
// working set is ONE z's A-panels (4MB) + W (2MB) ~= L2-fit, instead of 3 z at once (18MB).
struct Gemm3 {
  const u16* A[3];
  const u16* W[3];
  const float* bias[3];
  void* C[3];
};

template<int OUT_F32, int BM, int BN, int NZ, int MINW>
__global__ __launch_bounds__(256, MINW) void gemm_nt_bias(Gemm3 g) {
  constexpr int K = 1024, N = 1024;
  constexpr int BK = 64;
  constexpr int WM = BM / 32, WN = BN / 32;       // frags per wave (M, N)
  __shared__ __align__(16) u16 As[2][BM][BK];
  __shared__ __align__(16) u16 Bs[2][BN][BK];
  const int tid = threadIdx.x, lane = tid & 63, wave = tid >> 6;
  const int lr = lane & 15, lg = lane >> 4;
  const int wr = (wave >> 1) * (WM * 16), wc = (wave & 1) * (WN * 16);
  const int bm = blockIdx.x * BM, bn = blockIdx.y * BN;
  const int srow = lane >> 3;                 // staging: 8 rows x 8 chunks of 16B per issue
  const int schunk = (lane & 7) ^ srow;       // inverse-swizzled source chunk

  for (int z = 0; z < NZ; z++) {
    const u16* __restrict__ A = g.A[z];
    const u16* __restrict__ W = g.W[z];
    const float* __restrict__ bias = g.bias[z];

    f32x4 acc[WM][WN] = {};

    auto STAGE = [&](int k0, int bufi) {
#pragma unroll
      for (int i = 0; i < BM / 32; i++) {
        int r = wave * (BM / 4) + i * 8;
        gload16(A + (size_t)(bm + r + srow) * K + k0 + schunk * 8, &As[bufi][r][0]);
      }
#pragma unroll
      for (int i = 0; i < BN / 32; i++) {
        int r = wave * (BN / 4) + i * 8;
        gload16(W + (size_t)(bn + r + srow) * K + k0 + schunk * 8, &Bs[bufi][r][0]);
      }
    };

    STAGE(0, 0);
    __syncthreads();   // tile 0 ready (barrier drains vmcnt)
    int buf = 0;

    for (int k0 = 0; k0 < K; k0 += BK) {
      if (k0 + BK < K) STAGE(k0 + BK, buf ^ 1);   // prefetch completes under compute
      bfrag8 af[2][WM], bf[2][WN];
#pragma unroll
      for (int ks = 0; ks < 2; ks++) {
#pragma unroll
        for (int mi = 0; mi < WM; mi++) {
          const int row = wr + mi * 16 + lr;
          af[ks][mi] = *(const bfrag8*)&As[buf][row][((ks * 4 + lg) ^ (row & 7)) * 8];
        }
#pragma unroll
        for (int ni = 0; ni < WN; ni++) {
          const int row = wc + ni * 16 + lr;
          bf[ks][ni] = *(const bfrag8*)&Bs[buf][row][((ks * 4 + lg) ^ (row & 7)) * 8];
        }
      }
#pragma unroll
      for (int ks = 0; ks < 2; ks++)
#pragma unroll
        for (int mi = 0; mi < WM; mi++)
#pragma unroll
          for (int ni = 0; ni < WN; ni++)
            acc[mi][ni] = __builtin_amdgcn_mfma_f32_16x16x32_bf16(af[ks][mi], bf[ks][ni], acc[mi][ni], 0, 0, 0);
      __syncthreads();   // drains prefetch + buffer handoff (also isolates z iterations)
      buf ^= 1;
    }

    const int col0 = bn + wc + lr;
#pragma unroll
    for (int ni = 0; ni < WN; ni++) {
      int col = col0 + ni * 16;
      float bv = bias[col];
#pragma unroll
      for (int mi = 0; mi < WM; mi++) {
        int row = bm + wr + mi * 16 + lg * 4;
#pragma unroll
        for (int r = 0; r < 4; r++) {
          float v = acc[mi][ni][r] + bv;
          if (OUT_F32)
            ((float*)g.C[z])[(size_t)(row + r) * N + col] = v;
          else
            ((u16*)g.C[z])[(size_t)(row + r) * N + col] = f2bf(v);
        }
      }
    }
  }
}

// ---------------- V transpose: per bh, (2048,64) -> VT[64][2048]; also zeroes work-queue ctrs ----
__global__ void vtrans_kernel(const u16* __restrict__ Vp, u16* __restrict__ VT,
                              unsigned* __restrict__ ctr) {
  if (blockIdx.x == 0 && blockIdx.y == 0 && threadIdx.x < 8) ctr[threadIdx.x * 16] = 0u;
  __shared__ u16 T[64][66];
  const int kt = blockIdx.x, bh = blockIdx.y;
  const int tid = threadIdx.x;
  const u16* src = Vp + (size_t)bh * 131072 + (size_t)kt * 64 * 64;
#pragma unroll
  for (int i = 0; i < 2; i++) {
    int u = tid + 256 * i;
    int row = u >> 3, c = (u & 7) * 8;
    u16x8 v = *(const u16x8*)(src + row * 64 + c);
#pragma unroll
    for (int j = 0; j < 8; j++) T[c + j][row] = v[j];
  }
  __syncthreads();
  u16* dst = VT + (size_t)bh * 131072 + (size_t)kt * 64;
#pragma unroll
  for (int i = 0; i < 2; i++) {
    int u = tid + 256 * i;
    int d = u >> 3, c = (u & 7) * 8;
    u16x8 o = *(const u16x8*)&T[d][c];
    *(u16x8*)(dst + (size_t)d * 2048 + c) = o;
  }
}

// ---------------- causal flash attention: KVBLK=128, split-PV, fixed-reference softmax ------
// (R17 proven artifact, byte-identical)
__global__ __launch_bounds__(256, 2) void attn_kernel(
    const u16* __restrict__ Qp, const u16* __restrict__ Kp,
    const u16* __restrict__ VT, u16* __restrict__ X,
    unsigned* __restrict__ ctr)
{
  __shared__ __align__(16) u16 Ks[2][128][64];  // 32 KB
  __shared__ __align__(16) u16 Vs[2][64][128];  // 32 KB (rows = d, 256B rows = 16 chunks)
  constexpr int LDP = 72;                        // 144B stride (9x16B)
  __shared__ __align__(16) u16 Ps[4][16][LDP];   // 9 KB, per-wave P half-tile (16 q x 64 kpos)
  __shared__ unsigned s_unit;

  const int tid = threadIdx.x, lane = tid & 63, w = tid >> 6;
  const int lr = lane & 15, lg = lane >> 4;
  const int grp = (int)(blockIdx.x & 7);
  unsigned* __restrict__ gctr = ctr + grp * 16;   // 64B-spaced per-group counters
  // K staging (64B rows): 8 rows x 8 chunks per issue
  const int srow8 = lane >> 3;
  const int schunk8 = (lane & 7) ^ srow8;
  // V staging (256B rows): 4 rows x 16 chunks per issue; swizzle key row&15
  const int srow4 = lane >> 4;
  const int lane16 = lane & 15;
  const float C2 = 0.045084939f;    // (1/sqrt(1024)) * log2(e): softmax in log2 domain

  for (;;) {
    __syncthreads();                 // previous unit's LDS reads + s_unit use complete
    if (tid == 0) s_unit = atomicAdd(gctr, 1u);
    __syncthreads();
    const unsigned u = s_unit;
    if (u >= 128u) return;
    const int j = 31 - (int)(u >> 2);           // heavy-first within group
    const int bh = grp * 4 + (int)(u & 3u);     // group-local heads -> XCD L2 locality
    const size_t base = (size_t)bh * 131072;
    const u16* __restrict__ Qb = Qp + base;
    const u16* __restrict__ Kb = Kp + base;
    const u16* __restrict__ Vtb = VT + base;
    const int qrow0 = j * 64 + w * 16;          // wave's first q row
    const int q = qrow0 + lr;                   // this lane's q row (swapped layout)

    bfrag8 qf[2];
#pragma unroll
    for (int ds = 0; ds < 2; ds++)
      qf[ds] = *(const bfrag8*)(Qb + (size_t)(qrow0 + lr) * 64 + ds * 32 + lg * 8);

    f32x4 oacc[4] = {};                          // O^T: col=q(lr), row d=df*16+lg*4+r
    float l_run = 0.f;                           // per-lane partial (this lg quarter of kpos)

    auto STAGE = [&](int kt, int bufi) {
      // K rows kt*128 + [w*32, +32): 4 issues of 8 rows
#pragma unroll
      for (int i = 0; i < 4; i++) {
        int r = w * 32 + i * 8;
        gload16(Kb + (size_t)(kt * 128 + r + srow8) * 64 + schunk8 * 8, &Ks[bufi][r][0]);
      }
      // V rows (d) [w*16, +16): 4 issues of 4 rows; source chunk inverse-swizzled by row&15
#pragma unroll
      for (int i = 0; i < 4; i++) {
        int r = w * 16 + i * 4;
        int row = r + srow4;
        gload16(Vtb + (size_t)row * 2048 + kt * 128 + (lane16 ^ (row & 15)) * 8,
                &Vs[bufi][r][0]);
      }
    };

    const int ktmax = (j * 64 + 63) >> 7;        // last 128-kpos tile

    STAGE(0, 0);
    __syncthreads();   // tile 0 ready
    int buf = 0;

    for (int kt = 0; kt <= ktmax; kt++) {
      if (kt < ktmax) STAGE(kt + 1, buf ^ 1);   // prefetch completes under compute

      // ---- S^T = K Q^T : sacc[kf][r] = S[kpos = kt*128+kf*16+lg*4+r][q], kf=0..7 ----
      f32x4 sacc[8];
#pragma unroll
      for (int kf = 0; kf < 8; kf++) sacc[kf] = (f32x4){0.f, 0.f, 0.f, 0.f};
      __builtin_amdgcn_s_setprio(1);
#pragma unroll
      for (int kf = 0; kf < 8; kf++) {
        const int krow = kf * 16 + lr;
        bfrag8 kb0 = *(const bfrag8*)&Ks[buf][krow][((lg) ^ (krow & 7)) * 8];
        bfrag8 kb1 = *(const bfrag8*)&Ks[buf][krow][((lg + 4) ^ (krow & 7)) * 8];
        sacc[kf] = __builtin_amdgcn_mfma_f32_16x16x32_bf16(kb0, qf[0], sacc[kf], 0, 0, 0);
        sacc[kf] = __builtin_amdgcn_mfma_f32_16x16x32_bf16(kb1, qf[1], sacc[kf], 0, 0, 0);
      }
      __builtin_amdgcn_s_setprio(0);

      // ---- causal mask (only the last tile can mask) ----
      if (kt == ktmax) {
#pragma unroll
        for (int kf = 0; kf < 8; kf++)
#pragma unroll
          for (int r = 0; r < 4; r++) {
            int kg = kt * 128 + kf * 16 + lg * 4 + r;
            if (kg > q) sacc[kf][r] = -INFINITY;
          }
      }

      // ---- fixed-reference softmax: p = exp2(s*C2); no max tracking, no rescale ----
      float rs = 0.f;
#pragma unroll
      for (int h = 0; h < 2; h++) {
        // P for this 64-kpos half -> per-wave Ps
#pragma unroll
        for (int kf2 = 0; kf2 < 4; kf2++) {
          const int kf = h * 4 + kf2;
          float p0 = __builtin_amdgcn_exp2f(sacc[kf][0] * C2);
          float p1 = __builtin_amdgcn_exp2f(sacc[kf][1] * C2);
          float p2 = __builtin_amdgcn_exp2f(sacc[kf][2] * C2);
          float p3 = __builtin_amdgcn_exp2f(sacc[kf][3] * C2);
          rs += (p0 + p1) + (p2 + p3);
          uint2 pk;
          pk.x = cvtpk_bf16(p0, p1);
          pk.y = cvtpk_bf16(p2, p3);
          *(uint2*)&Ps[w][lr][kf2 * 16 + lg * 4] = pk;
        }
        // O^T += V^T P for this half (wave-internal ds ordering)
        __builtin_amdgcn_s_setprio(1);
#pragma unroll
        for (int ks = 0; ks < 2; ks++) {
          bfrag8 pa = *(const bfrag8*)&Ps[w][lr][ks * 32 + lg * 8];
#pragma unroll
          for (int df = 0; df < 4; df++) {
            const int vrow = df * 16 + lr;
            bfrag8 vf = *(const bfrag8*)&Vs[buf][vrow][((h * 8 + ks * 4 + lg) ^ (vrow & 15)) * 8];
            oacc[df] = __builtin_amdgcn_mfma_f32_16x16x32_bf16(vf, pa, oacc[df], 0, 0, 0);
          }
        }
        __builtin_amdgcn_s_setprio(0);
      }
      l_run += rs;

      __syncthreads();   // ONE drain per 128 kpos
      buf ^= 1;
    }

    // ---- reduce l once (lg quarters), normalize, write X ----
    l_run += __shfl_xor(l_run, 16);
    l_run += __shfl_xor(l_run, 32);
    float inv = 1.0f / l_run;
#pragma unroll
    for (int df = 0; df < 4; df++) {
      u16x4 o;
#pragma unroll
      for (int r = 0; r < 4; r++) o[r] = f2bf(oacc[df][r] * inv);
      *(u16x4*)&X[base + (size_t)q * 64 + df * 16 + lg * 4] = o;
    }
  }
}

extern "C" void kernel_launch(void* const* d_in, const int* in_sizes, int n_in,
                              void* d_out, int out_size, void* d_ws, size_t ws_size,
                              hipStream_t stream) {
  const float* key   = (const float*)d_in[0];
  const float* query = (const float*)d_in[1];
  const float* value = (const float*)d_in[2];
  const float* Wq = (const float*)d_in[4];
  const float* bq = (const float*)d_in[5];
  const float* Wk = (const float*)d_in[6];
  const float* bk = (const float*)d_in[7];
  const float* Wv = (const float*)d_in[8];
  const float* bv = (const float*)d_in[9];
  const float* Wo = (const float*)d_in[10];
  const float* bo = (const float*)d_in[11];

  u16* ws = (u16*)d_ws;
  const size_t MD = 4096ull * 1024ull;
  u16* qb  = ws;                   // query bf16 (dead after g1; first 512B reused as queue ctrs)
  u16* kb  = ws + MD;
  u16* vbf = ws + 2 * MD;          // value bf16 (reused as VT after g1)
  u16* Qp  = ws + 3 * MD;
  u16* Kp  = ws + 4 * MD;
  u16* Vp  = ws + 5 * MD;
  u16* Xb  = ws + 6 * MD;
  u16* wqb = ws + 7 * MD;
  u16* wkb = wqb + 1024 * 1024;
  u16* wvb = wkb + 1024 * 1024;
  u16* wob = wvb + 1024 * 1024;

  CvtBatch cb;
  cb.j[0] = { query, qb, 1048576 };
  cb.j[1] = { key,   kb, 1048576 };
  cb.j[2] = { value, vbf, 1048576 };
  cb.j[3] = { Wq, wqb, 262144 };
  cb.j[4] = { Wk, wkb, 262144 };
  cb.j[5] = { Wv, wvb, 262144 };
  cb.j[6] = { Wo, wob, 262144 };
  cvt_batch<<<dim3(4096, 7), 256, 0, stream>>>(cb);

  Gemm3 g1;
  g1.A[0] = qb;  g1.A[1] = kb;  g1.A[2] = vbf;
  g1.W[0] = wqb; g1.W[1] = wkb; g1.W[2] = wvb;
  g1.bias[0] = bq; g1.bias[1] = bk; g1.bias[2] = bv;
  g1.C[0] = Qp; g1.C[1] = Kp; g1.C[2] = Vp;
  gemm_nt_bias<0, 128, 64, 3, 2><<<dim3(32, 16), 256, 0, stream>>>(g1);

  u16* VT = vbf;
  unsigned* ctr = (unsigned*)qb;   // qb dead after g1
  vtrans_kernel<<<dim3(32, 32), 256, 0, stream>>>(Vp, VT, ctr);

  attn_kernel<<<512, 256, 0, stream>>>(Qp, Kp, VT, Xb, ctr);

  Gemm3 g2;
  g2.A[0] = Xb; g2.W[0] = wob; g2.bias[0] = bo; g2.C[0] = d_out;
  g2.A[1] = g2.A[2] = nullptr; g2.W[1] = g2.W[2] = nullptr;
  g2.bias[1] = g2.bias[2] = nullptr; g2.C[1] = g2.C[2] = nullptr;
  gemm_nt_bias<1, 128, 64, 1, 2><<<dim3(32, 16), 256, 0, stream>>>(g2);
}

// Round 19
// 121.974 us; speedup vs baseline: 1.0626x; 1.0626x over previous
//
#include <hip/hip_runtime.h>
#include <stdint.h>

typedef unsigned short u16;
typedef __attribute__((ext_vector_type(8))) short bfrag8;       // 8 x bf16 (MFMA operand)
typedef __attribute__((ext_vector_type(4))) float f32x4;        // MFMA accumulator
typedef __attribute__((ext_vector_type(8))) unsigned short u16x8;
typedef __attribute__((ext_vector_type(4))) unsigned short u16x4;

__device__ __forceinline__ u16 f2bf(float f) {
  union { float f; uint32_t u; } v; v.f = f;
  return (u16)((v.u + 0x7FFFu + ((v.u >> 16) & 1u)) >> 16);   // RNE
}

// v_cvt_pk_bf16_f32: lo16=bf16(a), hi16=bf16(b) (no builtin on gfx950 -- T12 recipe)
__device__ __forceinline__ uint32_t cvtpk_bf16(float a, float b) {
  uint32_t r;
  asm("v_cvt_pk_bf16_f32 %0, %1, %2" : "=v"(r) : "v"(a), "v"(b));
  return r;
}

// async global->LDS, 16B per lane; LDS dest is wave-uniform base + lane*16
__device__ __forceinline__ void gload16(const void* g, void* l) {
  __builtin_amdgcn_global_load_lds(
      (const __attribute__((address_space(1))) void*)g,
      (__attribute__((address_space(3))) void*)l, 16, 0, 0);
}

// ---------------- fp32 -> bf16 convert, batched (7 tensors, 1 launch) ----------------
struct CvtJob { const float* src; u16* dst; int n4; };
struct CvtBatch { CvtJob j[7]; };

__global__ void cvt_batch(CvtBatch b) {
  CvtJob jb = b.j[blockIdx.y];
  int i = blockIdx.x * blockDim.x + threadIdx.x;
  if (i >= jb.n4) return;
  float4 v = reinterpret_cast<const float4*>(jb.src)[i];
  u16x4 o;
  o[0] = f2bf(v.x); o[1] = f2bf(v.y); o[2] = f2bf(v.z); o[3] = f2bf(v.w);
  reinterpret_cast<u16x4*>(jb.dst)[i] = o;
}

// ---------------- NT GEMM: C = A(M,K) @ W(N,K)^T + bias ----------------
// R10 K-loop (gload_lds staging, BK=64, XOR chunk swizzle, T3-minimal prefetch).
// R19: g1 tile 128x128 (MFMA/barrier 2x, A re-reads halved); z back in the grid (R18 lesson:
// in-kernel z-loop trades residency for locality at a net loss).
struct Gemm3 {
  const u16* A[3];
  const u16* W[3];
  const float* bias[3];
  void* C[3];
};

template<int OUT_F32, int BM, int BN, int MINW>
__global__ __launch_bounds__(256, MINW) void gemm_nt_bias(Gemm3 g) {
  constexpr int K = 1024, N = 1024;
  constexpr int BK = 64;
  constexpr int WM = BM / 32, WN = BN / 32;       // frags per wave (M, N)
  __shared__ __align__(16) u16 As[2][BM][BK];
  __shared__ __align__(16) u16 Bs[2][BN][BK];
  const int z = blockIdx.z;
  const u16* __restrict__ A = g.A[z];
  const u16* __restrict__ W = g.W[z];
  const float* __restrict__ bias = g.bias[z];
  const int tid = threadIdx.x, lane = tid & 63, wave = tid >> 6;
  const int lr = lane & 15, lg = lane >> 4;
  const int wr = (wave >> 1) * (WM * 16), wc = (wave & 1) * (WN * 16);
  const int bm = blockIdx.x * BM, bn = blockIdx.y * BN;
  const int srow = lane >> 3;                 // staging: 8 rows x 8 chunks of 16B per issue
  const int schunk = (lane & 7) ^ srow;       // inverse-swizzled source chunk

  f32x4 acc[WM][WN] = {};

  auto STAGE = [&](int k0, int bufi) {
#pragma unroll
    for (int i = 0; i < BM / 32; i++) {
      int r = wave * (BM / 4) + i * 8;
      gload16(A + (size_t)(bm + r + srow) * K + k0 + schunk * 8, &As[bufi][r][0]);
    }
#pragma unroll
    for (int i = 0; i < BN / 32; i++) {
      int r = wave * (BN / 4) + i * 8;
      gload16(W + (size_t)(bn + r + srow) * K + k0 + schunk * 8, &Bs[bufi][r][0]);
    }
  };

  STAGE(0, 0);
  __syncthreads();   // tile 0 ready (barrier drains vmcnt)
  int buf = 0;

  for (int k0 = 0; k0 < K; k0 += BK) {
    if (k0 + BK < K) STAGE(k0 + BK, buf ^ 1);   // prefetch completes under compute
    bfrag8 af[2][WM], bf[2][WN];
#pragma unroll
    for (int ks = 0; ks < 2; ks++) {
#pragma unroll
      for (int mi = 0; mi < WM; mi++) {
        const int row = wr + mi * 16 + lr;
        af[ks][mi] = *(const bfrag8*)&As[buf][row][((ks * 4 + lg) ^ (row & 7)) * 8];
      }
#pragma unroll
      for (int ni = 0; ni < WN; ni++) {
        const int row = wc + ni * 16 + lr;
        bf[ks][ni] = *(const bfrag8*)&Bs[buf][row][((ks * 4 + lg) ^ (row & 7)) * 8];
      }
    }
#pragma unroll
    for (int ks = 0; ks < 2; ks++)
#pragma unroll
      for (int mi = 0; mi < WM; mi++)
#pragma unroll
        for (int ni = 0; ni < WN; ni++)
          acc[mi][ni] = __builtin_amdgcn_mfma_f32_16x16x32_bf16(af[ks][mi], bf[ks][ni], acc[mi][ni], 0, 0, 0);
    __syncthreads();   // drains prefetch + buffer handoff
    buf ^= 1;
  }

  const int col0 = bn + wc + lr;
#pragma unroll
  for (int ni = 0; ni < WN; ni++) {
    int col = col0 + ni * 16;
    float bv = bias[col];
#pragma unroll
    for (int mi = 0; mi < WM; mi++) {
      int row = bm + wr + mi * 16 + lg * 4;
#pragma unroll
      for (int r = 0; r < 4; r++) {
        float v = acc[mi][ni][r] + bv;
        if (OUT_F32)
          ((float*)g.C[z])[(size_t)(row + r) * N + col] = v;
        else
          ((u16*)g.C[z])[(size_t)(row + r) * N + col] = f2bf(v);
      }
    }
  }
}

// ---------------- V transpose: per bh, (2048,64) -> VT[64][2048]; also zeroes work-queue ctrs ----
__global__ void vtrans_kernel(const u16* __restrict__ Vp, u16* __restrict__ VT,
                              unsigned* __restrict__ ctr) {
  if (blockIdx.x == 0 && blockIdx.y == 0 && threadIdx.x < 8) ctr[threadIdx.x * 16] = 0u;
  __shared__ u16 T[64][66];
  const int kt = blockIdx.x, bh = blockIdx.y;
  const int tid = threadIdx.x;
  const u16* src = Vp + (size_t)bh * 131072 + (size_t)kt * 64 * 64;
#pragma unroll
  for (int i = 0; i < 2; i++) {
    int u = tid + 256 * i;
    int row = u >> 3, c = (u & 7) * 8;
    u16x8 v = *(const u16x8*)(src + row * 64 + c);
#pragma unroll
    for (int j = 0; j < 8; j++) T[c + j][row] = v[j];
  }
  __syncthreads();
  u16* dst = VT + (size_t)bh * 131072 + (size_t)kt * 64;
#pragma unroll
  for (int i = 0; i < 2; i++) {
    int u = tid + 256 * i;
    int d = u >> 3, c = (u & 7) * 8;
    u16x8 o = *(const u16x8*)&T[d][c];
    *(u16x8*)(dst + (size_t)d * 2048 + c) = o;
  }
}

// ---------------- causal flash attention: KVBLK=128, split-PV, fixed-reference softmax ------
// (R17 proven artifact, byte-identical)
__global__ __launch_bounds__(256, 2) void attn_kernel(
    const u16* __restrict__ Qp, const u16* __restrict__ Kp,
    const u16* __restrict__ VT, u16* __restrict__ X,
    unsigned* __restrict__ ctr)
{
  __shared__ __align__(16) u16 Ks[2][128][64];  // 32 KB
  __shared__ __align__(16) u16 Vs[2][64][128];  // 32 KB (rows = d, 256B rows = 16 chunks)
  constexpr int LDP = 72;                        // 144B stride (9x16B)
  __shared__ __align__(16) u16 Ps[4][16][LDP];   // 9 KB, per-wave P half-tile (16 q x 64 kpos)
  __shared__ unsigned s_unit;

  const int tid = threadIdx.x, lane = tid & 63, w = tid >> 6;
  const int lr = lane & 15, lg = lane >> 4;
  const int grp = (int)(blockIdx.x & 7);
  unsigned* __restrict__ gctr = ctr + grp * 16;   // 64B-spaced per-group counters
  // K staging (64B rows): 8 rows x 8 chunks per issue
  const int srow8 = lane >> 3;
  const int schunk8 = (lane & 7) ^ srow8;
  // V staging (256B rows): 4 rows x 16 chunks per issue; swizzle key row&15
  const int srow4 = lane >> 4;
  const int lane16 = lane & 15;
  const float C2 = 0.045084939f;    // (1/sqrt(1024)) * log2(e): softmax in log2 domain

  for (;;) {
    __syncthreads();                 // previous unit's LDS reads + s_unit use complete
    if (tid == 0) s_unit = atomicAdd(gctr, 1u);
    __syncthreads();
    const unsigned u = s_unit;
    if (u >= 128u) return;
    const int j = 31 - (int)(u >> 2);           // heavy-first within group
    const int bh = grp * 4 + (int)(u & 3u);     // group-local heads -> XCD L2 locality
    const size_t base = (size_t)bh * 131072;
    const u16* __restrict__ Qb = Qp + base;
    const u16* __restrict__ Kb = Kp + base;
    const u16* __restrict__ Vtb = VT + base;
    const int qrow0 = j * 64 + w * 16;          // wave's first q row
    const int q = qrow0 + lr;                   // this lane's q row (swapped layout)

    bfrag8 qf[2];
#pragma unroll
    for (int ds = 0; ds < 2; ds++)
      qf[ds] = *(const bfrag8*)(Qb + (size_t)(qrow0 + lr) * 64 + ds * 32 + lg * 8);

    f32x4 oacc[4] = {};                          // O^T: col=q(lr), row d=df*16+lg*4+r
    float l_run = 0.f;                           // per-lane partial (this lg quarter of kpos)

    auto STAGE = [&](int kt, int bufi) {
      // K rows kt*128 + [w*32, +32): 4 issues of 8 rows
#pragma unroll
      for (int i = 0; i < 4; i++) {
        int r = w * 32 + i * 8;
        gload16(Kb + (size_t)(kt * 128 + r + srow8) * 64 + schunk8 * 8, &Ks[bufi][r][0]);
      }
      // V rows (d) [w*16, +16): 4 issues of 4 rows; source chunk inverse-swizzled by row&15
#pragma unroll
      for (int i = 0; i < 4; i++) {
        int r = w * 16 + i * 4;
        int row = r + srow4;
        gload16(Vtb + (size_t)row * 2048 + kt * 128 + (lane16 ^ (row & 15)) * 8,
                &Vs[bufi][r][0]);
      }
    };

    const int ktmax = (j * 64 + 63) >> 7;        // last 128-kpos tile

    STAGE(0, 0);
    __syncthreads();   // tile 0 ready
    int buf = 0;

    for (int kt = 0; kt <= ktmax; kt++) {
      if (kt < ktmax) STAGE(kt + 1, buf ^ 1);   // prefetch completes under compute

      // ---- S^T = K Q^T : sacc[kf][r] = S[kpos = kt*128+kf*16+lg*4+r][q], kf=0..7 ----
      f32x4 sacc[8];
#pragma unroll
      for (int kf = 0; kf < 8; kf++) sacc[kf] = (f32x4){0.f, 0.f, 0.f, 0.f};
      __builtin_amdgcn_s_setprio(1);
#pragma unroll
      for (int kf = 0; kf < 8; kf++) {
        const int krow = kf * 16 + lr;
        bfrag8 kb0 = *(const bfrag8*)&Ks[buf][krow][((lg) ^ (krow & 7)) * 8];
        bfrag8 kb1 = *(const bfrag8*)&Ks[buf][krow][((lg + 4) ^ (krow & 7)) * 8];
        sacc[kf] = __builtin_amdgcn_mfma_f32_16x16x32_bf16(kb0, qf[0], sacc[kf], 0, 0, 0);
        sacc[kf] = __builtin_amdgcn_mfma_f32_16x16x32_bf16(kb1, qf[1], sacc[kf], 0, 0, 0);
      }
      __builtin_amdgcn_s_setprio(0);

      // ---- causal mask (only the last tile can mask) ----
      if (kt == ktmax) {
#pragma unroll
        for (int kf = 0; kf < 8; kf++)
#pragma unroll
          for (int r = 0; r < 4; r++) {
            int kg = kt * 128 + kf * 16 + lg * 4 + r;
            if (kg > q) sacc[kf][r] = -INFINITY;
          }
      }

      // ---- fixed-reference softmax: p = exp2(s*C2); no max tracking, no rescale ----
      float rs = 0.f;
#pragma unroll
      for (int h = 0; h < 2; h++) {
        // P for this 64-kpos half -> per-wave Ps
#pragma unroll
        for (int kf2 = 0; kf2 < 4; kf2++) {
          const int kf = h * 4 + kf2;
          float p0 = __builtin_amdgcn_exp2f(sacc[kf][0] * C2);
          float p1 = __builtin_amdgcn_exp2f(sacc[kf][1] * C2);
          float p2 = __builtin_amdgcn_exp2f(sacc[kf][2] * C2);
          float p3 = __builtin_amdgcn_exp2f(sacc[kf][3] * C2);
          rs += (p0 + p1) + (p2 + p3);
          uint2 pk;
          pk.x = cvtpk_bf16(p0, p1);
          pk.y = cvtpk_bf16(p2, p3);
          *(uint2*)&Ps[w][lr][kf2 * 16 + lg * 4] = pk;
        }
        // O^T += V^T P for this half (wave-internal ds ordering)
        __builtin_amdgcn_s_setprio(1);
#pragma unroll
        for (int ks = 0; ks < 2; ks++) {
          bfrag8 pa = *(const bfrag8*)&Ps[w][lr][ks * 32 + lg * 8];
#pragma unroll
          for (int df = 0; df < 4; df++) {
            const int vrow = df * 16 + lr;
            bfrag8 vf = *(const bfrag8*)&Vs[buf][vrow][((h * 8 + ks * 4 + lg) ^ (vrow & 15)) * 8];
            oacc[df] = __builtin_amdgcn_mfma_f32_16x16x32_bf16(vf, pa, oacc[df], 0, 0, 0);
          }
        }
        __builtin_amdgcn_s_setprio(0);
      }
      l_run += rs;

      __syncthreads();   // ONE drain per 128 kpos
      buf ^= 1;
    }

    // ---- reduce l once (lg quarters), normalize, write X ----
    l_run += __shfl_xor(l_run, 16);
    l_run += __shfl_xor(l_run, 32);
    float inv = 1.0f / l_run;
#pragma unroll
    for (int df = 0; df < 4; df++) {
      u16x4 o;
#pragma unroll
      for (int r = 0; r < 4; r++) o[r] = f2bf(oacc[df][r] * inv);
      *(u16x4*)&X[base + (size_t)q * 64 + df * 16 + lg * 4] = o;
    }
  }
}

extern "C" void kernel_launch(void* const* d_in, const int* in_sizes, int n_in,
                              void* d_out, int out_size, void* d_ws, size_t ws_size,
                              hipStream_t stream) {
  const float* key   = (const float*)d_in[0];
  const float* query = (const float*)d_in[1];
  const float* value = (const float*)d_in[2];
  const float* Wq = (const float*)d_in[4];
  const float* bq = (const float*)d_in[5];
  const float* Wk = (const float*)d_in[6];
  const float* bk = (const float*)d_in[7];
  const float* Wv = (const float*)d_in[8];
  const float* bv = (const float*)d_in[9];
  const float* Wo = (const float*)d_in[10];
  const float* bo = (const float*)d_in[11];

  u16* ws = (u16*)d_ws;
  const size_t MD = 4096ull * 1024ull;
  u16* qb  = ws;                   // query bf16 (dead after g1; first 512B reused as queue ctrs)
  u16* kb  = ws + MD;
  u16* vbf = ws + 2 * MD;          // value bf16 (reused as VT after g1)
  u16* Qp  = ws + 3 * MD;
  u16* Kp  = ws + 4 * MD;
  u16* Vp  = ws + 5 * MD;
  u16* Xb  = ws + 6 * MD;
  u16* wqb = ws + 7 * MD;
  u16* wkb = wqb + 1024 * 1024;
  u16* wvb = wkb + 1024 * 1024;
  u16* wob = wvb + 1024 * 1024;

  CvtBatch cb;
  cb.j[0] = { query, qb, 1048576 };
  cb.j[1] = { key,   kb, 1048576 };
  cb.j[2] = { value, vbf, 1048576 };
  cb.j[3] = { Wq, wqb, 262144 };
  cb.j[4] = { Wk, wkb, 262144 };
  cb.j[5] = { Wv, wvb, 262144 };
  cb.j[6] = { Wo, wob, 262144 };
  cvt_batch<<<dim3(4096, 7), 256, 0, stream>>>(cb);

  Gemm3 g1;
  g1.A[0] = qb;  g1.A[1] = kb;  g1.A[2] = vbf;
  g1.W[0] = wqb; g1.W[1] = wkb; g1.W[2] = wvb;
  g1.bias[0] = bq; g1.bias[1] = bk; g1.bias[2] = bv;
  g1.C[0] = Qp; g1.C[1] = Kp; g1.C[2] = Vp;
  gemm_nt_bias<0, 128, 128, 2><<<dim3(32, 8, 3), 256, 0, stream>>>(g1);

  u16* VT = vbf;
  unsigned* ctr = (unsigned*)qb;   // qb dead after g1
  vtrans_kernel<<<dim3(32, 32), 256, 0, stream>>>(Vp, VT, ctr);

  attn_kernel<<<512, 256, 0, stream>>>(Qp, Kp, VT, Xb, ctr);

  Gemm3 g2;
  g2.A[0] = Xb; g2.W[0] = wob; g2.bias[0] = bo; g2.C[0] = d_out;
  g2.A[1] = g2.A[2] = nullptr; g2.W[1] = g2.W[2] = nullptr;
  g2.bias[1] = g2.bias[2] = nullptr; g2.C[1] = g2.C[2] = nullptr;
  gemm_nt_bias<1, 128, 64, 3><<<dim3(32, 16, 1), 256, 0, stream>>>(g2);
}

// Round 20
// 118.073 us; speedup vs baseline: 1.0978x; 1.0330x over previous
//
#include <hip/hip_runtime.h>
#include <stdint.h>

typedef unsigned short u16;
typedef __attribute__((ext_vector_type(8))) short bfrag8;       // 8 x bf16 (MFMA operand)
typedef __attribute__((ext_vector_type(4))) float f32x4;        // MFMA accumulator
typedef __attribute__((ext_vector_type(8))) unsigned short u16x8;
typedef __attribute__((ext_vector_type(4))) unsigned short u16x4;

__device__ __forceinline__ u16 f2bf(float f) {
  union { float f; uint32_t u; } v; v.f = f;
  return (u16)((v.u + 0x7FFFu + ((v.u >> 16) & 1u)) >> 16);   // RNE
}

// v_cvt_pk_bf16_f32: lo16=bf16(a), hi16=bf16(b) (no builtin on gfx950 -- T12 recipe)
__device__ __forceinline__ uint32_t cvtpk_bf16(float a, float b) {
  uint32_t r;
  asm("v_cvt_pk_bf16_f32 %0, %1, %2" : "=v"(r) : "v"(a), "v"(b));
  return r;
}

// async global->LDS, 16B per lane; LDS dest is wave-uniform base + lane*16
__device__ __forceinline__ void gload16(const void* g, void* l) {
  __builtin_amdgcn_global_load_lds(
      (const __attribute__((address_space(1))) void*)g,
      (__attribute__((address_space(3))) void*)l, 16, 0, 0);
}

// ---------------- fp32 -> bf16 convert, batched (7 tensors, 1 launch) ----------------
struct CvtJob { const float* src; u16* dst; int n4; };
struct CvtBatch { CvtJob j[7]; };

__global__ void cvt_batch(CvtBatch b) {
  CvtJob jb = b.j[blockIdx.y];
  int i = blockIdx.x * blockDim.x + threadIdx.x;
  if (i >= jb.n4) return;
  float4 v = reinterpret_cast<const float4*>(jb.src)[i];
  u16x4 o;
  o[0] = f2bf(v.x); o[1] = f2bf(v.y); o[2] = f2bf(v.z); o[3] = f2bf(v.w);
  reinterpret_cast<u16x4*>(jb.dst)[i] = o;
}

// ---------------- NT GEMM: C = A(M,K) @ W(N,K)^T + bias ----------------
// R10/R17 artifact: gload_lds staging, BK=64, XOR chunk swizzle, T3-minimal prefetch.
// 128x64 tile @ 3 blocks/CU is the measured optimum of this template (R18 z-inside and
// R19 128x128 both regressed: kernel is latency/barrier-bound, not BW/ratio-bound).
struct Gemm3 {
  const u16* A[3];
  const u16* W[3];
  const float* bias[3];
  void* C[3];
};

template<int OUT_F32, int BM, int BN, int MINW>
__global__ __launch_bounds__(256, MINW) void gemm_nt_bias(Gemm3 g) {
  constexpr int K = 1024, N = 1024;
  constexpr int BK = 64;
  constexpr int WM = BM / 32, WN = BN / 32;       // frags per wave (M, N)
  __shared__ __align__(16) u16 As[2][BM][BK];
  __shared__ __align__(16) u16 Bs[2][BN][BK];
  const int z = blockIdx.z;
  const u16* __restrict__ A = g.A[z];
  const u16* __restrict__ W = g.W[z];
  const float* __restrict__ bias = g.bias[z];
  const int tid = threadIdx.x, lane = tid & 63, wave = tid >> 6;
  const int lr = lane & 15, lg = lane >> 4;
  const int wr = (wave >> 1) * (WM * 16), wc = (wave & 1) * (WN * 16);
  const int bm = blockIdx.x * BM, bn = blockIdx.y * BN;
  const int srow = lane >> 3;                 // staging: 8 rows x 8 chunks of 16B per issue
  const int schunk = (lane & 7) ^ srow;       // inverse-swizzled source chunk

  f32x4 acc[WM][WN] = {};

  auto STAGE = [&](int k0, int bufi) {
#pragma unroll
    for (int i = 0; i < BM / 32; i++) {
      int r = wave * (BM / 4) + i * 8;
      gload16(A + (size_t)(bm + r + srow) * K + k0 + schunk * 8, &As[bufi][r][0]);
    }
#pragma unroll
    for (int i = 0; i < BN / 32; i++) {
      int r = wave * (BN / 4) + i * 8;
      gload16(W + (size_t)(bn + r + srow) * K + k0 + schunk * 8, &Bs[bufi][r][0]);
    }
  };

  STAGE(0, 0);
  __syncthreads();   // tile 0 ready (barrier drains vmcnt)
  int buf = 0;

  for (int k0 = 0; k0 < K; k0 += BK) {
    if (k0 + BK < K) STAGE(k0 + BK, buf ^ 1);   // prefetch completes under compute
    bfrag8 af[2][WM], bf[2][WN];
#pragma unroll
    for (int ks = 0; ks < 2; ks++) {
#pragma unroll
      for (int mi = 0; mi < WM; mi++) {
        const int row = wr + mi * 16 + lr;
        af[ks][mi] = *(const bfrag8*)&As[buf][row][((ks * 4 + lg) ^ (row & 7)) * 8];
      }
#pragma unroll
      for (int ni = 0; ni < WN; ni++) {
        const int row = wc + ni * 16 + lr;
        bf[ks][ni] = *(const bfrag8*)&Bs[buf][row][((ks * 4 + lg) ^ (row & 7)) * 8];
      }
    }
#pragma unroll
    for (int ks = 0; ks < 2; ks++)
#pragma unroll
      for (int mi = 0; mi < WM; mi++)
#pragma unroll
        for (int ni = 0; ni < WN; ni++)
          acc[mi][ni] = __builtin_amdgcn_mfma_f32_16x16x32_bf16(af[ks][mi], bf[ks][ni], acc[mi][ni], 0, 0, 0);
    __syncthreads();   // drains prefetch + buffer handoff
    buf ^= 1;
  }

  const int col0 = bn + wc + lr;
#pragma unroll
  for (int ni = 0; ni < WN; ni++) {
    int col = col0 + ni * 16;
    float bv = bias[col];
#pragma unroll
    for (int mi = 0; mi < WM; mi++) {
      int row = bm + wr + mi * 16 + lg * 4;
#pragma unroll
      for (int r = 0; r < 4; r++) {
        float v = acc[mi][ni][r] + bv;
        if (OUT_F32)
          ((float*)g.C[z])[(size_t)(row + r) * N + col] = v;
        else
          ((u16*)g.C[z])[(size_t)(row + r) * N + col] = f2bf(v);
      }
    }
  }
}

// ---------------- V transpose: per bh, (2048,64) -> VT[64][2048]; also zeroes work-queue ctrs ----
__global__ void vtrans_kernel(const u16* __restrict__ Vp, u16* __restrict__ VT,
                              unsigned* __restrict__ ctr) {
  if (blockIdx.x == 0 && blockIdx.y == 0 && threadIdx.x < 8) ctr[threadIdx.x * 16] = 0u;
  __shared__ u16 T[64][66];
  const int kt = blockIdx.x, bh = blockIdx.y;
  const int tid = threadIdx.x;
  const u16* src = Vp + (size_t)bh * 131072 + (size_t)kt * 64 * 64;
#pragma unroll
  for (int i = 0; i < 2; i++) {
    int u = tid + 256 * i;
    int row = u >> 3, c = (u & 7) * 8;
    u16x8 v = *(const u16x8*)(src + row * 64 + c);
#pragma unroll
    for (int j = 0; j < 8; j++) T[c + j][row] = v[j];
  }
  __syncthreads();
  u16* dst = VT + (size_t)bh * 131072 + (size_t)kt * 64;
#pragma unroll
  for (int i = 0; i < 2; i++) {
    int u = tid + 256 * i;
    int d = u >> 3, c = (u & 7) * 8;
    u16x8 o = *(const u16x8*)&T[d][c];
    *(u16x8*)(dst + (size_t)d * 2048 + c) = o;
  }
}

// ---------------- causal flash attention: KVBLK=128, split-PV, fixed-reference softmax ------
// (R17 proven artifact, byte-identical)
__global__ __launch_bounds__(256, 2) void attn_kernel(
    const u16* __restrict__ Qp, const u16* __restrict__ Kp,
    const u16* __restrict__ VT, u16* __restrict__ X,
    unsigned* __restrict__ ctr)
{
  __shared__ __align__(16) u16 Ks[2][128][64];  // 32 KB
  __shared__ __align__(16) u16 Vs[2][64][128];  // 32 KB (rows = d, 256B rows = 16 chunks)
  constexpr int LDP = 72;                        // 144B stride (9x16B)
  __shared__ __align__(16) u16 Ps[4][16][LDP];   // 9 KB, per-wave P half-tile (16 q x 64 kpos)
  __shared__ unsigned s_unit;

  const int tid = threadIdx.x, lane = tid & 63, w = tid >> 6;
  const int lr = lane & 15, lg = lane >> 4;
  const int grp = (int)(blockIdx.x & 7);
  unsigned* __restrict__ gctr = ctr + grp * 16;   // 64B-spaced per-group counters
  // K staging (64B rows): 8 rows x 8 chunks per issue
  const int srow8 = lane >> 3;
  const int schunk8 = (lane & 7) ^ srow8;
  // V staging (256B rows): 4 rows x 16 chunks per issue; swizzle key row&15
  const int srow4 = lane >> 4;
  const int lane16 = lane & 15;
  const float C2 = 0.045084939f;    // (1/sqrt(1024)) * log2(e): softmax in log2 domain

  for (;;) {
    __syncthreads();                 // previous unit's LDS reads + s_unit use complete
    if (tid == 0) s_unit = atomicAdd(gctr, 1u);
    __syncthreads();
    const unsigned u = s_unit;
    if (u >= 128u) return;
    const int j = 31 - (int)(u >> 2);           // heavy-first within group
    const int bh = grp * 4 + (int)(u & 3u);     // group-local heads -> XCD L2 locality
    const size_t base = (size_t)bh * 131072;
    const u16* __restrict__ Qb = Qp + base;
    const u16* __restrict__ Kb = Kp + base;
    const u16* __restrict__ Vtb = VT + base;
    const int qrow0 = j * 64 + w * 16;          // wave's first q row
    const int q = qrow0 + lr;                   // this lane's q row (swapped layout)

    bfrag8 qf[2];
#pragma unroll
    for (int ds = 0; ds < 2; ds++)
      qf[ds] = *(const bfrag8*)(Qb + (size_t)(qrow0 + lr) * 64 + ds * 32 + lg * 8);

    f32x4 oacc[4] = {};                          // O^T: col=q(lr), row d=df*16+lg*4+r
    float l_run = 0.f;                           // per-lane partial (this lg quarter of kpos)

    auto STAGE = [&](int kt, int bufi) {
      // K rows kt*128 + [w*32, +32): 4 issues of 8 rows
#pragma unroll
      for (int i = 0; i < 4; i++) {
        int r = w * 32 + i * 8;
        gload16(Kb + (size_t)(kt * 128 + r + srow8) * 64 + schunk8 * 8, &Ks[bufi][r][0]);
      }
      // V rows (d) [w*16, +16): 4 issues of 4 rows; source chunk inverse-swizzled by row&15
#pragma unroll
      for (int i = 0; i < 4; i++) {
        int r = w * 16 + i * 4;
        int row = r + srow4;
        gload16(Vtb + (size_t)row * 2048 + kt * 128 + (lane16 ^ (row & 15)) * 8,
                &Vs[bufi][r][0]);
      }
    };

    const int ktmax = (j * 64 + 63) >> 7;        // last 128-kpos tile

    STAGE(0, 0);
    __syncthreads();   // tile 0 ready
    int buf = 0;

    for (int kt = 0; kt <= ktmax; kt++) {
      if (kt < ktmax) STAGE(kt + 1, buf ^ 1);   // prefetch completes under compute

      // ---- S^T = K Q^T : sacc[kf][r] = S[kpos = kt*128+kf*16+lg*4+r][q], kf=0..7 ----
      f32x4 sacc[8];
#pragma unroll
      for (int kf = 0; kf < 8; kf++) sacc[kf] = (f32x4){0.f, 0.f, 0.f, 0.f};
      __builtin_amdgcn_s_setprio(1);
#pragma unroll
      for (int kf = 0; kf < 8; kf++) {
        const int krow = kf * 16 + lr;
        bfrag8 kb0 = *(const bfrag8*)&Ks[buf][krow][((lg) ^ (krow & 7)) * 8];
        bfrag8 kb1 = *(const bfrag8*)&Ks[buf][krow][((lg + 4) ^ (krow & 7)) * 8];
        sacc[kf] = __builtin_amdgcn_mfma_f32_16x16x32_bf16(kb0, qf[0], sacc[kf], 0, 0, 0);
        sacc[kf] = __builtin_amdgcn_mfma_f32_16x16x32_bf16(kb1, qf[1], sacc[kf], 0, 0, 0);
      }
      __builtin_amdgcn_s_setprio(0);

      // ---- causal mask (only the last tile can mask) ----
      if (kt == ktmax) {
#pragma unroll
        for (int kf = 0; kf < 8; kf++)
#pragma unroll
          for (int r = 0; r < 4; r++) {
            int kg = kt * 128 + kf * 16 + lg * 4 + r;
            if (kg > q) sacc[kf][r] = -INFINITY;
          }
      }

      // ---- fixed-reference softmax: p = exp2(s*C2); no max tracking, no rescale ----
      float rs = 0.f;
#pragma unroll
      for (int h = 0; h < 2; h++) {
        // P for this 64-kpos half -> per-wave Ps
#pragma unroll
        for (int kf2 = 0; kf2 < 4; kf2++) {
          const int kf = h * 4 + kf2;
          float p0 = __builtin_amdgcn_exp2f(sacc[kf][0] * C2);
          float p1 = __builtin_amdgcn_exp2f(sacc[kf][1] * C2);
          float p2 = __builtin_amdgcn_exp2f(sacc[kf][2] * C2);
          float p3 = __builtin_amdgcn_exp2f(sacc[kf][3] * C2);
          rs += (p0 + p1) + (p2 + p3);
          uint2 pk;
          pk.x = cvtpk_bf16(p0, p1);
          pk.y = cvtpk_bf16(p2, p3);
          *(uint2*)&Ps[w][lr][kf2 * 16 + lg * 4] = pk;
        }
        // O^T += V^T P for this half (wave-internal ds ordering)
        __builtin_amdgcn_s_setprio(1);
#pragma unroll
        for (int ks = 0; ks < 2; ks++) {
          bfrag8 pa = *(const bfrag8*)&Ps[w][lr][ks * 32 + lg * 8];
#pragma unroll
          for (int df = 0; df < 4; df++) {
            const int vrow = df * 16 + lr;
            bfrag8 vf = *(const bfrag8*)&Vs[buf][vrow][((h * 8 + ks * 4 + lg) ^ (vrow & 15)) * 8];
            oacc[df] = __builtin_amdgcn_mfma_f32_16x16x32_bf16(vf, pa, oacc[df], 0, 0, 0);
          }
        }
        __builtin_amdgcn_s_setprio(0);
      }
      l_run += rs;

      __syncthreads();   // ONE drain per 128 kpos
      buf ^= 1;
    }

    // ---- reduce l once (lg quarters), normalize, write X ----
    l_run += __shfl_xor(l_run, 16);
    l_run += __shfl_xor(l_run, 32);
    float inv = 1.0f / l_run;
#pragma unroll
    for (int df = 0; df < 4; df++) {
      u16x4 o;
#pragma unroll
      for (int r = 0; r < 4; r++) o[r] = f2bf(oacc[df][r] * inv);
      *(u16x4*)&X[base + (size_t)q * 64 + df * 16 + lg * 4] = o;
    }
  }
}

extern "C" void kernel_launch(void* const* d_in, const int* in_sizes, int n_in,
                              void* d_out, int out_size, void* d_ws, size_t ws_size,
                              hipStream_t stream) {
  const float* key   = (const float*)d_in[0];
  const float* query = (const float*)d_in[1];
  const float* value = (const float*)d_in[2];
  const float* Wq = (const float*)d_in[4];
  const float* bq = (const float*)d_in[5];
  const float* Wk = (const float*)d_in[6];
  const float* bk = (const float*)d_in[7];
  const float* Wv = (const float*)d_in[8];
  const float* bv = (const float*)d_in[9];
  const float* Wo = (const float*)d_in[10];
  const float* bo = (const float*)d_in[11];

  u16* ws = (u16*)d_ws;
  const size_t MD = 4096ull * 1024ull;
  u16* qb  = ws;                   // query bf16 (dead after g1; first 512B reused as queue ctrs)
  u16* kb  = ws + MD;
  u16* vbf = ws + 2 * MD;          // value bf16 (reused as VT after g1)
  u16* Qp  = ws + 3 * MD;
  u16* Kp  = ws + 4 * MD;
  u16* Vp  = ws + 5 * MD;
  u16* Xb  = ws + 6 * MD;
  u16* wqb = ws + 7 * MD;
  u16* wkb = wqb + 1024 * 1024;
  u16* wvb = wkb + 1024 * 1024;
  u16* wob = wvb + 1024 * 1024;

  CvtBatch cb;
  cb.j[0] = { query, qb, 1048576 };
  cb.j[1] = { key,   kb, 1048576 };
  cb.j[2] = { value, vbf, 1048576 };
  cb.j[3] = { Wq, wqb, 262144 };
  cb.j[4] = { Wk, wkb, 262144 };
  cb.j[5] = { Wv, wvb, 262144 };
  cb.j[6] = { Wo, wob, 262144 };
  cvt_batch<<<dim3(4096, 7), 256, 0, stream>>>(cb);

  Gemm3 g1;
  g1.A[0] = qb;  g1.A[1] = kb;  g1.A[2] = vbf;
  g1.W[0] = wqb; g1.W[1] = wkb; g1.W[2] = wvb;
  g1.bias[0] = bq; g1.bias[1] = bk; g1.bias[2] = bv;
  g1.C[0] = Qp; g1.C[1] = Kp; g1.C[2] = Vp;
  gemm_nt_bias<0, 128, 64, 3><<<dim3(32, 16, 3), 256, 0, stream>>>(g1);

  u16* VT = vbf;
  unsigned* ctr = (unsigned*)qb;   // qb dead after g1
  vtrans_kernel<<<dim3(32, 32), 256, 0, stream>>>(Vp, VT, ctr);

  attn_kernel<<<512, 256, 0, stream>>>(Qp, Kp, VT, Xb, ctr);

  Gemm3 g2;
  g2.A[0] = Xb; g2.W[0] = wob; g2.bias[0] = bo; g2.C[0] = d_out;
  g2.A[1] = g2.A[2] = nullptr; g2.W[1] = g2.W[2] = nullptr;
  g2.bias[1] = g2.bias[2] = nullptr; g2.C[1] = g2.C[2] = nullptr;
  gemm_nt_bias<1, 128, 64, 3><<<dim3(32, 16, 1), 256, 0, stream>>>(g2);
}